// Round 12
// baseline (2486.023 us; speedup 1.0000x reference)
//
#include <hip/hip_runtime.h>
#include <hip/hip_fp16.h>
#include <stdint.h>

#define B_TOTAL 1024
#define T_TOTAL 1024
#define LOG2E 1.44269504088896f

typedef _Float16 f16x2 __attribute__((ext_vector_type(2)));

__device__ __forceinline__ float dot2w(uint32_t xw, uint32_t ww, float acc) {
#if __has_builtin(__builtin_amdgcn_fdot2)
    return __builtin_amdgcn_fdot2(__builtin_bit_cast(f16x2, xw),
                                  __builtin_bit_cast(f16x2, ww), acc, false);
#else
    f16x2 xv = __builtin_bit_cast(f16x2, xw);
    f16x2 wv = __builtin_bit_cast(f16x2, ww);
    return acc + (float)xv.x * (float)wv.x + (float)xv.y * (float)wv.y;
#endif
}

__device__ __forceinline__ uint32_t packf2(float a, float b) {
    f16x2 t;
    t.x = (_Float16)a;
    t.y = (_Float16)b;
    return __builtin_bit_cast(uint32_t, t);
}

__device__ __forceinline__ float sigm_(float z) {
    float e = __builtin_amdgcn_exp2f(-LOG2E * z);
    return __builtin_amdgcn_rcpf(1.0f + e);
}
__device__ __forceinline__ float tanh_(float z) {
    float e = __builtin_amdgcn_exp2f((2.0f * LOG2E) * z);
    float r = __builtin_amdgcn_rcpf(1.0f + e);
    return __builtin_fmaf(-2.0f, r, 1.0f);
}

// ============ fused producer/consumer LSTM, round 12 ============
// r11 structure (every component HW-proven separately: spin protocol r2/r3,
// asm-pinned weights r4, stride-4B ring r9-lesson, bpermute exchange r10)
// + hang-proofing after two container failures:
//  - BOUNDED spin loops (guard counters): a protocol hang now terminates
//    with wrong data (-> passed:false + absmax diagnostic) instead of
//    wedging the container. Zero cost when healthy.
//  - __align__(16) on LDS arrays; s_sleep in consumer re-poll.
template <int DIN, int H, bool LAYER1, bool STORE_ALL>
__global__ void __launch_bounds__(128) lstm_fused2(
    const float* __restrict__ x,              // LAYER1: [B][T][8] f32
    const __half* __restrict__ inbuf,         // layers>1: [T][B][DIN] f16
    const float* __restrict__ wihf, const float* __restrict__ whhf,
    const float* __restrict__ bihf, const float* __restrict__ bhhf,
    const float* __restrict__ wihb, const float* __restrict__ whhb,
    const float* __restrict__ bihb, const float* __restrict__ bhhb,
    __half* __restrict__ outbuf,              // STORE_ALL: [T][B][2H] f16
    float* __restrict__ lasth)                // !STORE_ALL: [B][H] f32
{
    constexpr int GPW   = 64 / H;     // batch groups per wave (3 or 6)
    constexpr int ND    = DIN / 2;    // input dwords (f16 pairs)
    constexpr int NH    = H / 2;      // h pair-dwords
    constexpr int SLOTS = 16;

    const int dir  = blockIdx.y;
    const int lane = threadIdx.x;
    const int wv   = threadIdx.y;     // 0 = consumer (scan), 1 = producer
    const int g    = lane / H;
    const int j    = lane - g * H;
    const int gs   = (g < GPW) ? g : (GPW - 1);
    const int b    = blockIdx.x * GPW + g;
    const bool valid = (g < GPW) && (b < B_TOTAL);
    const int bs   = valid ? b : (B_TOTAL - 1);

    __shared__ __align__(16) uint32_t ringA[SLOTS][64];  // packf2(a0,a1)
    __shared__ __align__(16) uint32_t ringB[SLOTS][64];  // packf2(a2,a3)
    __shared__ __align__(16) int      flags[SLOTS];
    __shared__ int consprog;

    volatile uint32_t* vra  = &ringA[0][0];
    volatile uint32_t* vrb  = &ringB[0][0];
    volatile int*      vflg = flags;
    volatile int*      vcons = &consprog;

    if (wv == 0) {
        if (lane < SLOTS) flags[lane] = 0;
        if (lane == 0) consprog = -1;
    }
    __syncthreads();

    const int tstep = dir ? -1 : 1;

    if (wv == 1) {
        // ------------------------- producer -------------------------
        const float* w_ih = dir ? wihb : wihf;

        uint32_t wih2[4][ND];
#pragma unroll
        for (int q = 0; q < 4; ++q) {
            const int r = q * H + j;
#pragma unroll
            for (int d = 0; d < ND; ++d)
                wih2[q][d] = packf2(w_ih[r * DIN + 2 * d], w_ih[r * DIN + 2 * d + 1]);
        }
        // opaque pin: no remat of weights inside the loop (r0-r3 lesson)
#pragma unroll
        for (int q = 0; q < 4; ++q)
#pragma unroll
            for (int d = 0; d < ND; ++d) asm volatile("" : "+v"(wih2[q][d]));

        auto emit = [&](int s, float a0, float a1, float a2, float a3) {
            if (s >= SLOTS) {
                int guard = 1 << 20;        // bounded: hang -> wrong data, not wedge
                while (*vcons < s - SLOTS && --guard) __builtin_amdgcn_s_sleep(2);
            }
            const int slot = s & (SLOTS - 1);
            vra[slot * 64 + lane] = packf2(a0, a1);
            vrb[slot * 64 + lane] = packf2(a2, a3);
            vflg[slot] = s + 1;   // release: per-wave DS ops complete in order
        };

        if constexpr (LAYER1) {
            const float* xrow = x + (size_t)bs * (T_TOTAL * 8);
            int tt = dir ? (T_TOTAL - 1) : 0;
            uint32_t xv[8];   // [0..3]=cur, [4..7]=lag
            {
                const float4* pp = (const float4*)(xrow + (size_t)tt * 8);
                float4 u0 = pp[0], u1 = pp[1];
                xv[0] = packf2(u0.x, u0.y); xv[1] = packf2(u0.z, u0.w);
                xv[2] = packf2(u1.x, u1.y); xv[3] = packf2(u1.z, u1.w);
                if (dir) {
                    const float4* qq = (const float4*)(xrow + (size_t)(tt - 1) * 8);
                    float4 v0 = qq[0], v1 = qq[1];
                    xv[4] = packf2(v0.x, v0.y); xv[5] = packf2(v0.z, v0.w);
                    xv[6] = packf2(v1.x, v1.y); xv[7] = packf2(v1.z, v1.w);
                } else {
#pragma unroll
                    for (int d = 4; d < 8; ++d) xv[d] = 0u;
                }
            }

            for (int s = 0; s < T_TOTAL; ++s) {
                float a0 = 0.f, a1 = 0.f, a2 = 0.f, a3 = 0.f;
#pragma unroll
                for (int d = 0; d < 8; ++d) {
                    a0 = dot2w(xv[d], wih2[0][d], a0);
                    a1 = dot2w(xv[d], wih2[1][d], a1);
                    a2 = dot2w(xv[d], wih2[2][d], a2);
                    a3 = dot2w(xv[d], wih2[3][d], a3);
                }

                const int li = dir ? (tt - 2) : (tt + 1);
                const bool ld = (li >= 0) && (li < T_TOTAL);
                float4 n0 = {0, 0, 0, 0}, n1 = {0, 0, 0, 0};
                if (ld) {
                    const float4* pp = (const float4*)(xrow + (size_t)li * 8);
                    n0 = pp[0];
                    n1 = pp[1];
                }

                emit(s, a0, a1, a2, a3);

                uint32_t np[4] = {packf2(n0.x, n0.y), packf2(n0.z, n0.w),
                                  packf2(n1.x, n1.y), packf2(n1.z, n1.w)};
                if (dir == 0) {
#pragma unroll
                    for (int d = 0; d < 4; ++d) { xv[4 + d] = xv[d]; xv[d] = np[d]; }
                } else {
#pragma unroll
                    for (int d = 0; d < 4; ++d) {
                        xv[d] = xv[4 + d];
                        xv[4 + d] = ld ? np[d] : 0u;
                    }
                }
                tt += tstep;
            }
        } else {
            const ptrdiff_t ipstep = (ptrdiff_t)tstep * (B_TOTAL * ND);
            const uint32_t* ip = (const uint32_t*)inbuf +
                (size_t)(dir ? (T_TOTAL - 1) : 0) * (B_TOTAL * ND) + (size_t)bs * ND;

            uint32_t xq0[ND], xq1[ND];
#pragma unroll
            for (int d = 0; d < ND; ++d) xq0[d] = ip[d];
            ip += ipstep;
#pragma unroll
            for (int d = 0; d < ND; ++d) xq1[d] = ip[d];
            ip += ipstep;

            auto pstep = [&](uint32_t* xc, int s, bool pf) {
                float a0 = 0.f, a1 = 0.f, a2 = 0.f, a3 = 0.f;
#pragma unroll
                for (int d = 0; d < ND; ++d) {
                    a0 = dot2w(xc[d], wih2[0][d], a0);
                    a1 = dot2w(xc[d], wih2[1][d], a1);
                    a2 = dot2w(xc[d], wih2[2][d], a2);
                    a3 = dot2w(xc[d], wih2[3][d], a3);
                }
                if (pf) {
#pragma unroll
                    for (int d = 0; d < ND; ++d) xc[d] = ip[d];
                    ip += ipstep;
                }
                emit(s, a0, a1, a2, a3);
            };

            for (int s = 0; s < T_TOTAL; s += 2) {
                pstep(xq0, s, s + 2 < T_TOTAL);
                pstep(xq1, s + 1, s + 3 < T_TOTAL);
            }
        }
    } else {
        // ------------------------- consumer -------------------------
        const float* w_hh = dir ? whhb : whhf;
        const float* b_i  = dir ? bihb : bihf;
        const float* b_h  = dir ? bhhb : bhhf;

        uint32_t whh2[4][NH];
        float bias[4];
#pragma unroll
        for (int q = 0; q < 4; ++q) {
            const int r = q * H + j;
#pragma unroll
            for (int k = 0; k < NH; ++k)
                whh2[q][k] = packf2(w_hh[r * H + 2 * k], w_hh[r * H + 2 * k + 1]);
            bias[q] = b_i[r] + b_h[r];
        }
#pragma unroll
        for (int q = 0; q < 4; ++q) {
#pragma unroll
            for (int k = 0; k < NH; ++k) asm volatile("" : "+v"(whh2[q][k]));
            asm volatile("" : "+v"(bias[q]));
        }

        // h all-gather: DPP pair-swap + NH bpermute broadcasts (r10, conflict-free)
        const int  base4 = (gs * H) * 4;
        const bool evn   = ((lane & 1) == 0);
        uint32_t hd[NH];
        auto exchange = [&](float h) {
            const uint32_t hf = (uint32_t)__builtin_bit_cast(uint16_t, (_Float16)h);
            const uint32_t nb = (uint32_t)__builtin_amdgcn_mov_dpp(
                (int)hf, 0xB1 /*quad_perm [1,0,3,2]*/, 0xF, 0xF, true);
            const uint32_t lo = evn ? hf : nb;
            const uint32_t hi = evn ? nb : hf;
            const uint32_t pairw = lo | (hi << 16);
#pragma unroll
            for (int k = 0; k < NH; ++k)
                hd[k] = (uint32_t)__builtin_amdgcn_ds_bpermute(base4 + 8 * k, (int)pairw);
        };

        float c_st = 0.f;
        exchange(0.f);

        __half* op = nullptr;
        ptrdiff_t opstep = 0;
        if constexpr (STORE_ALL) {
            const int tstart = dir ? (T_TOTAL - 1) : 0;
            op = outbuf + (size_t)tstart * (B_TOTAL * 2 * H) +
                 (size_t)bs * (2 * H) + dir * H + j;
            opstep = (ptrdiff_t)tstep * (B_TOTAL * 2 * H);
        }

        // prefetch slot 0 (flag first, then data: acquire order)
        int fl_p = vflg[0];
        uint32_t paA = vra[lane];
        uint32_t paB = vrb[lane];

        float hl = 0.f;

        for (int s = 0; s < T_TOTAL; ++s) {
            const int slot = s & (SLOTS - 1);
            uint32_t ga = paA, gb = paB;
            int fl = fl_p;
            if (fl != s + 1) {              // producer behind: re-poll (bounded)
                int guard = 1 << 22;
                do {
                    __builtin_amdgcn_s_sleep(1);
                    fl = vflg[slot];
                    ga = vra[slot * 64 + lane];
                    gb = vrb[slot * 64 + lane];
                } while (fl != s + 1 && --guard);
            }
            {   // prefetch slot s+1 (latency hidden under this step)
                const int ns = (s + 1) & (SLOTS - 1);
                fl_p = vflg[ns];
                paA  = vra[ns * 64 + lane];
                paB  = vrb[ns * 64 + lane];
            }
            if ((s & 7) == 7) {
                if (lane == 0) *vcons = s;
            }

            const f16x2 p01 = __builtin_bit_cast(f16x2, ga);
            const f16x2 p23 = __builtin_bit_cast(f16x2, gb);
            float a0 = (float)p01.x + bias[0];
            float a1 = (float)p01.y + bias[1];
            float a2 = (float)p23.x + bias[2];
            float a3 = (float)p23.y + bias[3];
#pragma unroll
            for (int k = 0; k < NH; ++k) {
                a0 = dot2w(hd[k], whh2[0][k], a0);
                a1 = dot2w(hd[k], whh2[1][k], a1);
                a2 = dot2w(hd[k], whh2[2][k], a2);
                a3 = dot2w(hd[k], whh2[3][k], a3);
            }
            const float iv  = sigm_(a0);
            const float fv  = sigm_(a1);
            const float gg2 = tanh_(a2);
            const float ov  = sigm_(a3);
            c_st = __builtin_fmaf(fv, c_st, iv * gg2);
            const float h = ov * tanh_(c_st);

            if constexpr (STORE_ALL) {
                if (valid) *op = __float2half(h);
                op += opstep;
            }
            exchange(h);
            hl = h;
        }

        if constexpr (!STORE_ALL) {
            if (valid) lasth[b * H + j] = hl;
        }
    }
}

// L4 backward needed only at t=T-1 (single step from zero state) + FC + sigmoid.
__global__ void final_kernel(const __half* __restrict__ l3out,  // [T][B][20] f16
                             const float* __restrict__ hf4,     // [B][10]
                             const float* __restrict__ w_ih,    // w4b_ih [40][20]
                             const float* __restrict__ b_ih,
                             const float* __restrict__ b_hh,
                             const float* __restrict__ fc_w,    // [20]
                             const float* __restrict__ fc_b,
                             float* __restrict__ out)           // [B]
{
    const int b = blockIdx.x * blockDim.x + threadIdx.x;
    if (b >= B_TOTAL) return;

    float in4[20];
    const __half* p = l3out + (size_t)(T_TOTAL - 1) * (B_TOTAL * 20) + (size_t)b * 20;
#pragma unroll
    for (int i = 0; i < 20; ++i) in4[i] = __half2float(p[i]);

    float z = fc_b[0];
#pragma unroll
    for (int k = 0; k < 10; ++k) z += fc_w[k] * hf4[b * 10 + k];

#pragma unroll
    for (int k = 0; k < 10; ++k) {
        float gi = b_ih[k]      + b_hh[k];
        float gg = b_ih[20 + k] + b_hh[20 + k];
        float go = b_ih[30 + k] + b_hh[30 + k];
#pragma unroll
        for (int i = 0; i < 20; ++i) {
            const float xi = in4[i];
            gi += w_ih[k * 20 + i]        * xi;
            gg += w_ih[(20 + k) * 20 + i] * xi;
            go += w_ih[(30 + k) * 20 + i] * xi;
        }
        const float cc = sigm_(gi) * tanh_(gg);
        const float hb = sigm_(go) * tanh_(cc);
        z += fc_w[10 + k] * hb;
    }
    out[b] = sigm_(z);
}

extern "C" void kernel_launch(void* const* d_in, const int* in_sizes, int n_in,
                              void* d_out, int out_size, void* d_ws, size_t ws_size,
                              hipStream_t stream) {
    const float* x = (const float*)d_in[0];
    auto W = [&](int li, int dr, int k) -> const float* {
        return (const float*)d_in[1 + (li - 1) * 8 + dr * 4 + k];
    };
    const float* fc_w = (const float*)d_in[33];
    const float* fc_b = (const float*)d_in[34];
    float* out = (float*)d_out;

    // workspace = r4's exact proven layout (160.04 MiB):
    // hA [T][B][40] f16, hB [T][B][40] f16, hf4 [B][10] f32.
    __half* hA = (__half*)d_ws;
    __half* hB = hA + (size_t)T_TOTAL * B_TOTAL * 40;
    float* hf4 = (float*)(hB + (size_t)T_TOTAL * B_TOTAL * 40);

    // L1: DIN=16 (x + lag), H=20 -> hA [T][B][40]
    lstm_fused2<16, 20, true, true><<<dim3(342, 2), dim3(64, 2), 0, stream>>>(
        x, nullptr,
        W(1,0,0), W(1,0,1), W(1,0,2), W(1,0,3),
        W(1,1,0), W(1,1,1), W(1,1,2), W(1,1,3),
        hA, nullptr);

    // L2: DIN=40, H=20, hA -> hB [T][B][40]
    lstm_fused2<40, 20, false, true><<<dim3(342, 2), dim3(64, 2), 0, stream>>>(
        nullptr, hA,
        W(2,0,0), W(2,0,1), W(2,0,2), W(2,0,3),
        W(2,1,0), W(2,1,1), W(2,1,2), W(2,1,3),
        hB, nullptr);

    // L3: DIN=40, H=10, hB -> hA [T][B][20]
    lstm_fused2<40, 10, false, true><<<dim3(171, 2), dim3(64, 2), 0, stream>>>(
        nullptr, hB,
        W(3,0,0), W(3,0,1), W(3,0,2), W(3,0,3),
        W(3,1,0), W(3,1,1), W(3,1,2), W(3,1,3),
        hA, nullptr);

    // L4 forward only: DIN=20, H=10, hA -> hf4 [B][10]
    lstm_fused2<20, 10, false, false><<<dim3(171, 1), dim3(64, 2), 0, stream>>>(
        nullptr, hA,
        W(4,0,0), W(4,0,1), W(4,0,2), W(4,0,3),
        W(4,0,0), W(4,0,1), W(4,0,2), W(4,0,3), // dir=1 never launched
        nullptr, hf4);

    // L4 backward single step + FC + sigmoid
    final_kernel<<<dim3(4), 256, 0, stream>>>(
        hA, hf4, W(4,1,0), W(4,1,2), W(4,1,3), fc_w, fc_b, out);
}